// Round 3
// baseline (76.004 us; speedup 1.0000x reference)
//
#include <hip/hip_runtime.h>

// Problem constants (from reference): B=8, M=64, N=64, P=3, Q=3, GRID=512, DIM=3
#define GRID_PTS 512
#define M_CTRL   64
#define N_CTRL   64

// Native clang vector type — __builtin_nontemporal_store requires a real
// vector type, not HIP's HIP_vector_type class.
typedef float vfloat4 __attribute__((ext_vector_type(4)));

// One block per (b, g) row. Stage-1: 64 lanes compute Su[n] (u-direction
// contraction) into LDS. Stage-2: 128 threads each produce 4 consecutive h
// points (v-direction contraction + perspective divide) and store 48 B as
// three float4's (aligned: row base is 6144 B-aligned, thread offset 48t).
//
// R2/R3 micro-opts (kernel is latency-bound, ~6-10 us vs 4 us write floor):
//  - vspan/Nv prefetched BEFORE the barrier so stage-2 global-load latency
//    overlaps stage-1's ctrl loads.
//  - v_rcp_f32 via __builtin_amdgcn_rcpf (threshold 5.9e-2 >> 1e-7 rel err).
//  - non-temporal output stores: 25 MB streaming, never re-read.
__global__ __launch_bounds__(128) void surfeval_kernel(
    const float4* __restrict__ ctrl,   // (B, M, N) of float4 (xyz*w, w)
    const int*    __restrict__ uspan,  // (GRID)
    const int*    __restrict__ vspan,  // (GRID)
    const float4* __restrict__ Nu,     // (GRID) basis coeffs, 4 per g
    const float4* __restrict__ Nv,     // (GRID)
    float*        __restrict__ out)    // (B, GRID, GRID, 3)
{
    __shared__ float4 Su[N_CTRL];

    const int blk = blockIdx.x;            // b*GRID + g
    const int g   = blk & (GRID_PTS - 1);
    const int b   = blk >> 9;
    const int t   = threadIdx.x;
    const int h0  = t * 4;

    // ---- Prefetch stage-2 operands (latency hides behind stage 1) ----
    int    iv[4];
    float4 nv[4];
#pragma unroll
    for (int i = 0; i < 4; ++i) {
        iv[i] = vspan[h0 + i] - 3;
        nv[i] = Nv[h0 + i];
    }

    // ---- Stage 1: Su[n] = sum_r Nu[g][r] * ctrl[b][uspan[g]-3+r][n] ----
    if (t < N_CTRL) {
        const int    iu = uspan[g] - 3;
        const float4 nu = Nu[g];
        const float4* cp = ctrl + ((size_t)b * M_CTRL + iu) * N_CTRL + t;
        const float4 c0 = cp[0 * N_CTRL];
        const float4 c1 = cp[1 * N_CTRL];
        const float4 c2 = cp[2 * N_CTRL];
        const float4 c3 = cp[3 * N_CTRL];
        float4 s;
        s.x = nu.x * c0.x + nu.y * c1.x + nu.z * c2.x + nu.w * c3.x;
        s.y = nu.x * c0.y + nu.y * c1.y + nu.z * c2.y + nu.w * c3.y;
        s.z = nu.x * c0.z + nu.y * c1.z + nu.z * c2.z + nu.w * c3.z;
        s.w = nu.x * c0.w + nu.y * c1.w + nu.z * c2.w + nu.w * c3.w;
        Su[t] = s;
    }
    __syncthreads();

    // ---- Stage 2: 4 h-points per thread ----
    float r[12];
#pragma unroll
    for (int i = 0; i < 4; ++i) {
        const float4 a0 = Su[iv[i] + 0];
        const float4 a1 = Su[iv[i] + 1];
        const float4 a2 = Su[iv[i] + 2];
        const float4 a3 = Su[iv[i] + 3];
        const float4 n  = nv[i];
        const float sx = n.x * a0.x + n.y * a1.x + n.z * a2.x + n.w * a3.x;
        const float sy = n.x * a0.y + n.y * a1.y + n.z * a2.y + n.w * a3.y;
        const float sz = n.x * a0.z + n.y * a1.z + n.z * a2.z + n.w * a3.z;
        const float sw = n.x * a0.w + n.y * a1.w + n.z * a2.w + n.w * a3.w;
        const float inv = __builtin_amdgcn_rcpf(sw);
        r[i * 3 + 0] = sx * inv;
        r[i * 3 + 1] = sy * inv;
        r[i * 3 + 2] = sz * inv;
    }

    vfloat4* op = (vfloat4*)(out + ((size_t)blk * GRID_PTS + h0) * 3);
    vfloat4 o0 = { r[0], r[1], r[2],  r[3]  };
    vfloat4 o1 = { r[4], r[5], r[6],  r[7]  };
    vfloat4 o2 = { r[8], r[9], r[10], r[11] };
    __builtin_nontemporal_store(o0, op + 0);
    __builtin_nontemporal_store(o1, op + 1);
    __builtin_nontemporal_store(o2, op + 2);
}

extern "C" void kernel_launch(void* const* d_in, const int* in_sizes, int n_in,
                              void* d_out, int out_size, void* d_ws, size_t ws_size,
                              hipStream_t stream) {
    const float4* ctrl  = (const float4*)d_in[0];  // (8, 64, 64, 4) f32
    const int*    uspan = (const int*)d_in[1];     // (512)
    const int*    vspan = (const int*)d_in[2];     // (512)
    const float4* Nu    = (const float4*)d_in[3];  // (512, 4) f32
    const float4* Nv    = (const float4*)d_in[4];  // (512, 4) f32
    float*        out   = (float*)d_out;           // (8, 512, 512, 3) f32

    const int blocks = 8 * GRID_PTS;  // one per (b, g)
    surfeval_kernel<<<blocks, 128, 0, stream>>>(ctrl, uspan, vspan, Nu, Nv, out);
}